// Round 4
// baseline (412.147 us; speedup 1.0000x reference)
//
#include <hip/hip_runtime.h>
#include <cstdint>
#include <cstddef>

#define B_ 256
#define IW_ 3072
#define L_ 8
#define NN_ 7
#define FCIN_ 16384
#define OUTW_ 10
#define ICST 40   // ushorts per (row,col) cell: 32 ic + 8 pad

typedef short short8 __attribute__((ext_vector_type(8)));
typedef float f32x4 __attribute__((ext_vector_type(4)));

__device__ __forceinline__ ushort f2bf(float x) {
    uint u = __float_as_uint(x);
    return (ushort)((u + 0x7fffu + ((u >> 16) & 1u)) >> 16);
}
__device__ __forceinline__ float bf2f(ushort b) { return __uint_as_float(((uint)b) << 16); }

// ---------- repack conv1 weights: [512][3][3][3] -> [512][28] (27 taps + pad) ----------
__global__ void k_repack_w1(const float* __restrict__ w1, float* __restrict__ w1r) {
    int i = blockIdx.x * 256 + threadIdx.x;
    if (i >= 512 * 28) return;
    int o = i / 28, t = i % 28;
    w1r[i] = (t < 27) ? w1[o * 27 + t] : 0.f;
}

// ---------- repack conv2 weights into MFMA frag-linear hi/lo bf16 ----------
// layout: [l8][icc2][tap9][mt4][lane64][j8] (ushort);  oc = mt*16 + (lane&15); ic = icc*32 + (lane>>4)*8 + j
__global__ void k_repack_w2(const float* __restrict__ w2, ushort* __restrict__ w2h,
                            ushort* __restrict__ w2l) {
    int i = blockIdx.x * 256 + threadIdx.x;
    if (i >= 294912) return;
    int j    = i & 7;
    int lane = (i >> 3) & 63;
    int mt   = (i >> 9) & 3;
    int tap  = (i >> 11) % 9;
    int icc  = (i / 18432) & 1;
    int l    = i / 36864;
    int fr = lane & 15, fq = lane >> 4;
    int oc = mt * 16 + fr;
    int ic = icc * 32 + fq * 8 + j;
    float w = w2[(((size_t)l * 64 + oc) * 64 + ic) * 9 + tap];
    ushort hb = f2bf(w);
    w2h[i] = hb;
    w2l[i] = f2bf(w - bf2f(hb));
}

// ---------- mixture: per-sample soft tree weights [B][8] ----------
__global__ __launch_bounds__(256) void k_mixture(const float* __restrict__ x, const float* __restrict__ nw,
                                                 const float* __restrict__ nb, float* __restrict__ mix) {
    __shared__ float red[4 * NN_];
    __shared__ float bes[NN_];
    int b = blockIdx.x, tid = threadIdx.x;
    const float* xb = x + (size_t)b * IW_;
    float p[NN_];
#pragma unroll
    for (int n = 0; n < NN_; ++n) p[n] = 0.f;
    for (int i = tid; i < IW_; i += 256) {
        float xv = xb[i];
#pragma unroll
        for (int n = 0; n < NN_; ++n) p[n] = fmaf(xv, nw[n * IW_ + i], p[n]);
    }
#pragma unroll
    for (int n = 0; n < NN_; ++n) {
        float v = p[n];
        for (int off = 32; off > 0; off >>= 1) v += __shfl_xor(v, off);
        if ((tid & 63) == 0) red[(tid >> 6) * NN_ + n] = v;
    }
    __syncthreads();
    if (tid < NN_) {
        float s = red[tid] + red[NN_ + tid] + red[2 * NN_ + tid] + red[3 * NN_ + tid] + nb[tid];
        bes[tid] = 1.f / (1.f + expf(-s));
    }
    __syncthreads();
    if (tid < L_) {
        int leaf = tid;
        float b0 = bes[0];
        float t0 = ((leaf >> 2) & 1) ? b0 : 1.f - b0;
        float b1v = bes[1 + ((leaf >> 2) & 1)];
        float t1 = ((leaf >> 1) & 1) ? b1v : 1.f - b1v;
        float b2v = bes[3 + ((leaf >> 1) & 3)];
        float t2 = (leaf & 1) ? b2v : 1.f - b2v;
        mix[b * L_ + leaf] = t0 * t1 * t2;
    }
}

// ---------- fused conv1(+pool+relu) -> LDS -> conv2 MFMA + bias + relu + mixture reduce ----------
// grid = bc*2: block = (sample, leaf-half). Each block: 4 leaves x 2 icc = 8 steps.
// 2 blocks/CU co-resident (LDS 51.8 KB each) -> conv1 VALU of one overlaps conv2 MFMA of the other.
__global__ __launch_bounds__(512, 4) void k_fused(const float* __restrict__ x, const float* __restrict__ w1r,
                                                  const float* __restrict__ cb1,
                                                  const ushort* __restrict__ w2h, const ushort* __restrict__ w2l,
                                                  const float* __restrict__ cb2, const float* __restrict__ mixw,
                                                  float* __restrict__ out1, int boff) {
    __shared__ __align__(16) ushort smem[2 * 324 * ICST];   // 51.84 KB: yh | yl (xpad aliases front)
    ushort* yh = smem;
    ushort* yl = smem + 324 * ICST;
    float* xpad = (float*)smem;                              // 3*34*34 floats = 13.9 KB < yh plane

    int tid = threadIdx.x;
    int bl = blockIdx.x >> 1, half = blockIdx.x & 1;
    int b = boff + bl;
    int lane = tid & 63, wid = tid >> 6;
    int fr = lane & 15, fq = lane >> 4;
    int hh = tid >> 8;          // chan-half within icc chunk
    int p = tid & 255;          // pooled pos
    int pr = p >> 4, pc = p & 15;

    // ---- prologue: xpad (zero + fill) -> patch regs -> zero y planes ----
    for (int i = tid; i < 3 * 34 * 34; i += 512) xpad[i] = 0.f;
    __syncthreads();
    for (int i = tid; i < 3072; i += 512) {
        int ch = i >> 10, rr = (i >> 5) & 31, cc = i & 31;
        xpad[(ch * 34 + rr + 1) * 34 + cc + 1] = x[(size_t)b * IW_ + i];
    }
    __syncthreads();
    float pch[3][4][4];   // step-invariant patch, lives in regs for whole kernel
#pragma unroll
    for (int ch = 0; ch < 3; ++ch)
#pragma unroll
        for (int dr = 0; dr < 4; ++dr) {
            float2 v0 = *(const float2*)&xpad[(ch * 34 + 2 * pr + dr) * 34 + 2 * pc];
            float2 v1 = *(const float2*)&xpad[(ch * 34 + 2 * pr + dr) * 34 + 2 * pc + 2];
            pch[ch][dr][0] = v0.x; pch[ch][dr][1] = v0.y;
            pch[ch][dr][2] = v1.x; pch[ch][dr][3] = v1.y;
        }
    __syncthreads();
    {   // zero y planes (borders stay zero forever)
        uint4 z; z.x = z.y = z.z = z.w = 0u;
        for (int i = tid; i < (2 * 324 * ICST) / 8; i += 512) ((uint4*)smem)[i] = z;
    }
    __syncthreads();

    f32x4 acc[4][2], oacc[4][2];
#pragma unroll
    for (int mt = 0; mt < 4; ++mt)
#pragma unroll
        for (int nl = 0; nl < 2; ++nl) { acc[mt][nl] = (f32x4)0.f; oacc[mt][nl] = (f32x4)0.f; }

    const int yoff_w = ((pr + 1) * 18 + (pc + 1)) * ICST + hh * 16;

    for (int s = 0; s < 8; ++s) {
        int l = half * 4 + (s >> 1), icc = s & 1;
        // ---- conv1 phase: 16 chans, wave-uniform scalar weight loads ----
        int woff = __builtin_amdgcn_readfirstlane((l * 64 + icc * 32 + hh * 16) * 28);
        int boffc = __builtin_amdgcn_readfirstlane(l * 64 + icc * 32 + hh * 16);
        const float* wbase = w1r + woff;
        const float* bbase = cb1 + boffc;
        uint hp[8], lp[8];
#pragma unroll
        for (int q = 0; q < 8; ++q) { hp[q] = 0u; lp[q] = 0u; }
#pragma unroll 4
        for (int e = 0; e < 16; ++e) {
            float wq[28];
#pragma unroll
            for (int q = 0; q < 7; ++q) *(float4*)&wq[q * 4] = ((const float4*)(wbase + e * 28))[q];
            float a0 = 0.f, a1 = 0.f, a2 = 0.f, a3 = 0.f;
#pragma unroll
            for (int ch = 0; ch < 3; ++ch)
#pragma unroll
                for (int kh = 0; kh < 3; ++kh)
#pragma unroll
                    for (int kw = 0; kw < 3; ++kw) {
                        float w = wq[ch * 9 + kh * 3 + kw];
                        a0 = fmaf(w, pch[ch][kh][kw], a0);
                        a1 = fmaf(w, pch[ch][kh][kw + 1], a1);
                        a2 = fmaf(w, pch[ch][kh + 1][kw], a2);
                        a3 = fmaf(w, pch[ch][kh + 1][kw + 1], a3);
                    }
            float v = fmaxf(fmaxf(a0, a1), fmaxf(a2, a3)) + bbase[e];
            v = fmaxf(v, 0.f);
            ushort hb = f2bf(v);
            ushort lb = f2bf(v - bf2f(hb));
            hp[e >> 1] |= (uint)hb << (16 * (e & 1));
            lp[e >> 1] |= (uint)lb << (16 * (e & 1));
        }
        {
            uint4 H0, H1, L0v, L1v;
            H0.x = hp[0]; H0.y = hp[1]; H0.z = hp[2]; H0.w = hp[3];
            H1.x = hp[4]; H1.y = hp[5]; H1.z = hp[6]; H1.w = hp[7];
            L0v.x = lp[0]; L0v.y = lp[1]; L0v.z = lp[2]; L0v.w = lp[3];
            L1v.x = lp[4]; L1v.y = lp[5]; L1v.z = lp[6]; L1v.w = lp[7];
            *(uint4*)&yh[yoff_w] = H0; *(uint4*)&yh[yoff_w + 8] = H1;
            *(uint4*)&yl[yoff_w] = L0v; *(uint4*)&yl[yoff_w + 8] = L1v;
        }
        __syncthreads();

        // ---- conv2 MFMA phase: 9 taps, wave tile (4mt x 2nl) ----
        const ushort* wa_h = w2h + (size_t)((l * 2 + icc) * 9) * 4 * 512;
        const ushort* wa_l = w2l + (size_t)((l * 2 + icc) * 9) * 4 * 512;
#pragma unroll
        for (int kh = 0; kh < 3; ++kh)
#pragma unroll
            for (int kw = 0; kw < 3; ++kw) {
                int tap = kh * 3 + kw;
                short8 ah[4], al[4];
#pragma unroll
                for (int mt = 0; mt < 4; ++mt) {
                    ah[mt] = *(const short8*)(wa_h + ((size_t)(tap * 4 + mt) * 64 + lane) * 8);
                    al[mt] = *(const short8*)(wa_l + ((size_t)(tap * 4 + mt) * 64 + lane) * 8);
                }
#pragma unroll
                for (int nl = 0; nl < 2; ++nl) {
                    int off = (((wid * 2 + nl) + kh) * 18 + (fr + kw)) * ICST + fq * 8;
                    short8 bh = *(const short8*)(yh + off);
                    short8 bv = *(const short8*)(yl + off);
#pragma unroll
                    for (int mt = 0; mt < 4; ++mt) {
                        acc[mt][nl] = __builtin_amdgcn_mfma_f32_16x16x32_bf16(ah[mt], bh, acc[mt][nl], 0, 0, 0);
                        acc[mt][nl] = __builtin_amdgcn_mfma_f32_16x16x32_bf16(ah[mt], bv, acc[mt][nl], 0, 0, 0);
                        acc[mt][nl] = __builtin_amdgcn_mfma_f32_16x16x32_bf16(al[mt], bh, acc[mt][nl], 0, 0, 0);
                    }
                }
            }
        if (icc) {  // leaf epilogue: bias + relu + mixture accumulate
            float m = mixw[(size_t)b * 8 + l];
#pragma unroll
            for (int mt = 0; mt < 4; ++mt)
#pragma unroll
                for (int j = 0; j < 4; ++j) {
                    float bias = cb2[l * 64 + mt * 16 + fq * 4 + j];
#pragma unroll
                    for (int nl = 0; nl < 2; ++nl) {
                        float v = fmaxf(acc[mt][nl][j] + bias, 0.f);
                        oacc[mt][nl][j] = fmaf(m, v, oacc[mt][nl][j]);
                        acc[mt][nl][j] = 0.f;
                    }
                }
        }
        __syncthreads();
    }

    // ---- store partial out1 [blk][64 oc][256 pos] fp32 (two halves per sample) ----
#pragma unroll
    for (int mt = 0; mt < 4; ++mt)
#pragma unroll
        for (int nl = 0; nl < 2; ++nl)
#pragma unroll
            for (int j = 0; j < 4; ++j) {
                int oc = mt * 16 + fq * 4 + j;
                int pos = (wid * 2 + nl) * 16 + fr;
                out1[((size_t)blockIdx.x * 64 + oc) * 256 + pos] = oacc[mt][nl][j];
            }
}

// ---------- fc: sum two leaf-half partials, then [16384] @ [10][16384]^T + b ----------
__global__ __launch_bounds__(256) void k_fc(const float* __restrict__ out1, const float* __restrict__ fcw,
                                            const float* __restrict__ fcb, float* __restrict__ out, int boff) {
    __shared__ float red[4][OUTW_];
    int tid = threadIdx.x;
    int bl = blockIdx.x;
    const float4* f0 = (const float4*)(out1 + (size_t)(bl * 2) * FCIN_);
    const float4* f1 = (const float4*)(out1 + (size_t)(bl * 2 + 1) * FCIN_);
    float pj[OUTW_];
#pragma unroll
    for (int j = 0; j < OUTW_; ++j) pj[j] = 0.f;
    for (int i = tid; i < FCIN_ / 4; i += 256) {
        float4 v0 = f0[i], v1 = f1[i];
        float4 v;
        v.x = v0.x + v1.x; v.y = v0.y + v1.y; v.z = v0.z + v1.z; v.w = v0.w + v1.w;
#pragma unroll
        for (int j = 0; j < OUTW_; ++j) {
            float4 w = ((const float4*)(fcw + (size_t)j * FCIN_))[i];
            pj[j] += v.x * w.x + v.y * w.y + v.z * w.z + v.w * w.w;
        }
    }
#pragma unroll
    for (int j = 0; j < OUTW_; ++j) {
        float v = pj[j];
        for (int off = 32; off > 0; off >>= 1) v += __shfl_xor(v, off);
        if ((tid & 63) == 0) red[tid >> 6][j] = v;
    }
    __syncthreads();
    if (tid < OUTW_) {
        float s = red[0][tid] + red[1][tid] + red[2][tid] + red[3][tid] + fcb[tid];
        out[(size_t)(boff + bl) * OUTW_ + tid] = s;
    }
}

extern "C" void kernel_launch(void* const* d_in, const int* in_sizes, int n_in,
                              void* d_out, int out_size, void* d_ws, size_t ws_size,
                              hipStream_t stream) {
    const float* x   = (const float*)d_in[0];
    const float* nw  = (const float*)d_in[1];
    const float* nb  = (const float*)d_in[2];
    const float* w1  = (const float*)d_in[3];
    const float* cb1 = (const float*)d_in[4];
    const float* w2  = (const float*)d_in[5];
    const float* cb2 = (const float*)d_in[6];
    const float* fcw = (const float*)d_in[7];
    const float* fcb = (const float*)d_in[8];
    float* out = (float*)d_out;

    float*  ws  = (float*)d_ws;
    float*  mix = ws;                       // 2048 f
    float*  w1r = mix + 2048;               // 14336 f
    ushort* w2h = (ushort*)(w1r + 14336);   // 294912 us
    ushort* w2l = w2h + 294912;             // 294912 us
    float*  out1 = (float*)(w2l + 294912);  // Bc * 2 * 16384 f

    // fixed bytes: (2048+14336)*4 + 2*294912*2 = 1245184; out1 per sample = 131072 B
    long avail = (long)ws_size - 1245184L;
    int Bc = (int)(avail / 131072L);
    if (Bc > B_) Bc = B_;
    if (Bc < 1) Bc = 1;

    k_repack_w1<<<(512 * 28 + 255) / 256, 256, 0, stream>>>(w1, w1r);
    k_repack_w2<<<294912 / 256, 256, 0, stream>>>(w2, w2h, w2l);
    k_mixture<<<B_, 256, 0, stream>>>(x, nw, nb, mix);

    for (int boff = 0; boff < B_; boff += Bc) {
        int bc = (B_ - boff < Bc) ? (B_ - boff) : Bc;
        k_fused<<<bc * 2, 512, 0, stream>>>(x, w1r, cb1, w2h, w2l, cb2, mix, out1, boff);
        k_fc<<<bc, 256, 0, stream>>>(out1, fcw, fcb, out, boff);
    }
}

// Round 5
// 289.545 us; speedup vs baseline: 1.4234x; 1.4234x over previous
//
#include <hip/hip_runtime.h>
#include <cstdint>
#include <cstddef>

#define B_ 256
#define IW_ 3072
#define L_ 8
#define NN_ 7
#define FCIN_ 16384
#define OUTW_ 10
#define ICST 40   // ushorts per (row,col) cell: 32 ic + 8 pad

typedef short short8 __attribute__((ext_vector_type(8)));
typedef float f32x4 __attribute__((ext_vector_type(4)));

__device__ __forceinline__ ushort f2bf(float x) {
    uint u = __float_as_uint(x);
    return (ushort)((u + 0x7fffu + ((u >> 16) & 1u)) >> 16);
}
__device__ __forceinline__ float bf2f(ushort b) { return __uint_as_float(((uint)b) << 16); }

// ---------- repack conv1 weights: [512][3][3][3] -> [512][28] (27 taps + pad) ----------
__global__ void k_repack_w1(const float* __restrict__ w1, float* __restrict__ w1r) {
    int i = blockIdx.x * 256 + threadIdx.x;
    if (i >= 512 * 28) return;
    int o = i / 28, t = i % 28;
    w1r[i] = (t < 27) ? w1[o * 27 + t] : 0.f;
}

// ---------- repack conv2 weights into MFMA frag-linear hi/lo bf16 ----------
// layout: [l8][icc2][tap9][mt4][lane64][j8] (ushort);  oc = mt*16 + (lane&15); ic = icc*32 + (lane>>4)*8 + j
__global__ void k_repack_w2(const float* __restrict__ w2, ushort* __restrict__ w2h,
                            ushort* __restrict__ w2l) {
    int i = blockIdx.x * 256 + threadIdx.x;
    if (i >= 294912) return;
    int j    = i & 7;
    int lane = (i >> 3) & 63;
    int mt   = (i >> 9) & 3;
    int tap  = (i >> 11) % 9;
    int icc  = (i / 18432) & 1;
    int l    = i / 36864;
    int fr = lane & 15, fq = lane >> 4;
    int oc = mt * 16 + fr;
    int ic = icc * 32 + fq * 8 + j;
    float w = w2[(((size_t)l * 64 + oc) * 64 + ic) * 9 + tap];
    ushort hb = f2bf(w);
    w2h[i] = hb;
    w2l[i] = f2bf(w - bf2f(hb));
}

// ---------- mixture: per-sample soft tree weights [B][8] ----------
__global__ __launch_bounds__(256) void k_mixture(const float* __restrict__ x, const float* __restrict__ nw,
                                                 const float* __restrict__ nb, float* __restrict__ mix) {
    __shared__ float red[4 * NN_];
    __shared__ float bes[NN_];
    int b = blockIdx.x, tid = threadIdx.x;
    const float* xb = x + (size_t)b * IW_;
    float p[NN_];
#pragma unroll
    for (int n = 0; n < NN_; ++n) p[n] = 0.f;
    for (int i = tid; i < IW_; i += 256) {
        float xv = xb[i];
#pragma unroll
        for (int n = 0; n < NN_; ++n) p[n] = fmaf(xv, nw[n * IW_ + i], p[n]);
    }
#pragma unroll
    for (int n = 0; n < NN_; ++n) {
        float v = p[n];
        for (int off = 32; off > 0; off >>= 1) v += __shfl_xor(v, off);
        if ((tid & 63) == 0) red[(tid >> 6) * NN_ + n] = v;
    }
    __syncthreads();
    if (tid < NN_) {
        float s = red[tid] + red[NN_ + tid] + red[2 * NN_ + tid] + red[3 * NN_ + tid] + nb[tid];
        bes[tid] = 1.f / (1.f + expf(-s));
    }
    __syncthreads();
    if (tid < L_) {
        int leaf = tid;
        float b0 = bes[0];
        float t0 = ((leaf >> 2) & 1) ? b0 : 1.f - b0;
        float b1v = bes[1 + ((leaf >> 2) & 1)];
        float t1 = ((leaf >> 1) & 1) ? b1v : 1.f - b1v;
        float b2v = bes[3 + ((leaf >> 1) & 3)];
        float t2 = (leaf & 1) ? b2v : 1.f - b2v;
        mix[b * L_ + leaf] = t0 * t1 * t2;
    }
}

// ---------- fused conv1(+pool+relu) -> LDS -> conv2 MFMA + bias + relu + mixture reduce ----------
// grid = bc*2: block = (sample, leaf-half), 4 leaves x 2 icc = 8 steps.
// launch_bounds (512,2): VGPR budget 256 -> compiler ~116, NO spills; natural occupancy
// floor(512/116)=4 waves/SIMD = 2 blocks/CU (LDS 104 KB < 160) -> phases overlap across blocks.
__global__ __launch_bounds__(512, 2) void k_fused(const float* __restrict__ x, const float* __restrict__ w1r,
                                                  const float* __restrict__ cb1,
                                                  const ushort* __restrict__ w2h, const ushort* __restrict__ w2l,
                                                  const float* __restrict__ cb2, const float* __restrict__ mixw,
                                                  float* __restrict__ out1, int boff) {
    __shared__ __align__(16) ushort smem[2 * 324 * ICST];   // 51.84 KB: yh | yl (xpad aliases front)
    ushort* yh = smem;
    ushort* yl = smem + 324 * ICST;
    float* xpad = (float*)smem;                              // 3*34*34 floats = 13.9 KB < yh plane

    int tid = threadIdx.x;
    int bl = blockIdx.x >> 1, half = blockIdx.x & 1;
    int b = boff + bl;
    int lane = tid & 63, wid = tid >> 6;
    int fr = lane & 15, fq = lane >> 4;
    int hh = tid >> 8;          // chan-half within icc chunk
    int p = tid & 255;          // pooled pos
    int pr = p >> 4, pc = p & 15;

    // ---- prologue: xpad (zero + fill) -> patch regs -> zero y planes ----
    for (int i = tid; i < 3 * 34 * 34; i += 512) xpad[i] = 0.f;
    __syncthreads();
    for (int i = tid; i < 3072; i += 512) {
        int ch = i >> 10, rr = (i >> 5) & 31, cc = i & 31;
        xpad[(ch * 34 + rr + 1) * 34 + cc + 1] = x[(size_t)b * IW_ + i];
    }
    __syncthreads();
    float pch[3][4][4];   // step-invariant patch, lives in regs for whole kernel
#pragma unroll
    for (int ch = 0; ch < 3; ++ch)
#pragma unroll
        for (int dr = 0; dr < 4; ++dr) {
            float2 v0 = *(const float2*)&xpad[(ch * 34 + 2 * pr + dr) * 34 + 2 * pc];
            float2 v1 = *(const float2*)&xpad[(ch * 34 + 2 * pr + dr) * 34 + 2 * pc + 2];
            pch[ch][dr][0] = v0.x; pch[ch][dr][1] = v0.y;
            pch[ch][dr][2] = v1.x; pch[ch][dr][3] = v1.y;
        }
    __syncthreads();
    {   // zero y planes (borders stay zero forever)
        uint4 z; z.x = z.y = z.z = z.w = 0u;
        for (int i = tid; i < (2 * 324 * ICST) / 8; i += 512) ((uint4*)smem)[i] = z;
    }
    __syncthreads();

    f32x4 acc[4][2], oacc[4][2];
#pragma unroll
    for (int mt = 0; mt < 4; ++mt)
#pragma unroll
        for (int nl = 0; nl < 2; ++nl) { acc[mt][nl] = (f32x4)0.f; oacc[mt][nl] = (f32x4)0.f; }

    const int yoff_w = ((pr + 1) * 18 + (pc + 1)) * ICST + hh * 16;

    for (int s = 0; s < 8; ++s) {
        int l = half * 4 + (s >> 1), icc = s & 1;
        // ---- conv1 phase: 16 chans, wave-uniform scalar weight loads ----
        int woff = __builtin_amdgcn_readfirstlane((l * 64 + icc * 32 + hh * 16) * 28);
        int boffc = __builtin_amdgcn_readfirstlane(l * 64 + icc * 32 + hh * 16);
        const float* wbase = w1r + woff;
        const float* bbase = cb1 + boffc;
        uint hp[8], lp[8];
#pragma unroll
        for (int q = 0; q < 8; ++q) { hp[q] = 0u; lp[q] = 0u; }
#pragma unroll 4
        for (int e = 0; e < 16; ++e) {
            float wq[28];
#pragma unroll
            for (int q = 0; q < 7; ++q) *(float4*)&wq[q * 4] = ((const float4*)(wbase + e * 28))[q];
            float a0 = 0.f, a1 = 0.f, a2 = 0.f, a3 = 0.f;
#pragma unroll
            for (int ch = 0; ch < 3; ++ch)
#pragma unroll
                for (int kh = 0; kh < 3; ++kh)
#pragma unroll
                    for (int kw = 0; kw < 3; ++kw) {
                        float w = wq[ch * 9 + kh * 3 + kw];
                        a0 = fmaf(w, pch[ch][kh][kw], a0);
                        a1 = fmaf(w, pch[ch][kh][kw + 1], a1);
                        a2 = fmaf(w, pch[ch][kh + 1][kw], a2);
                        a3 = fmaf(w, pch[ch][kh + 1][kw + 1], a3);
                    }
            float v = fmaxf(fmaxf(a0, a1), fmaxf(a2, a3)) + bbase[e];
            v = fmaxf(v, 0.f);
            ushort hb = f2bf(v);
            ushort lb = f2bf(v - bf2f(hb));
            hp[e >> 1] |= (uint)hb << (16 * (e & 1));
            lp[e >> 1] |= (uint)lb << (16 * (e & 1));
        }
        {
            uint4 H0, H1, L0v, L1v;
            H0.x = hp[0]; H0.y = hp[1]; H0.z = hp[2]; H0.w = hp[3];
            H1.x = hp[4]; H1.y = hp[5]; H1.z = hp[6]; H1.w = hp[7];
            L0v.x = lp[0]; L0v.y = lp[1]; L0v.z = lp[2]; L0v.w = lp[3];
            L1v.x = lp[4]; L1v.y = lp[5]; L1v.z = lp[6]; L1v.w = lp[7];
            *(uint4*)&yh[yoff_w] = H0; *(uint4*)&yh[yoff_w + 8] = H1;
            *(uint4*)&yl[yoff_w] = L0v; *(uint4*)&yl[yoff_w + 8] = L1v;
        }
        __syncthreads();

        // ---- conv2 MFMA phase: 9 taps, wave tile (4mt x 2nl) ----
        const ushort* wa_h = w2h + (size_t)((l * 2 + icc) * 9) * 4 * 512;
        const ushort* wa_l = w2l + (size_t)((l * 2 + icc) * 9) * 4 * 512;
#pragma unroll
        for (int kh = 0; kh < 3; ++kh)
#pragma unroll
            for (int kw = 0; kw < 3; ++kw) {
                int tap = kh * 3 + kw;
                short8 ah[4], al[4];
#pragma unroll
                for (int mt = 0; mt < 4; ++mt) {
                    ah[mt] = *(const short8*)(wa_h + ((size_t)(tap * 4 + mt) * 64 + lane) * 8);
                    al[mt] = *(const short8*)(wa_l + ((size_t)(tap * 4 + mt) * 64 + lane) * 8);
                }
#pragma unroll
                for (int nl = 0; nl < 2; ++nl) {
                    int off = (((wid * 2 + nl) + kh) * 18 + (fr + kw)) * ICST + fq * 8;
                    short8 bh = *(const short8*)(yh + off);
                    short8 bv = *(const short8*)(yl + off);
#pragma unroll
                    for (int mt = 0; mt < 4; ++mt) {
                        acc[mt][nl] = __builtin_amdgcn_mfma_f32_16x16x32_bf16(ah[mt], bh, acc[mt][nl], 0, 0, 0);
                        acc[mt][nl] = __builtin_amdgcn_mfma_f32_16x16x32_bf16(ah[mt], bv, acc[mt][nl], 0, 0, 0);
                        acc[mt][nl] = __builtin_amdgcn_mfma_f32_16x16x32_bf16(al[mt], bh, acc[mt][nl], 0, 0, 0);
                    }
                }
            }
        if (icc) {  // leaf epilogue: bias + relu + mixture accumulate
            float m = mixw[(size_t)b * 8 + l];
#pragma unroll
            for (int mt = 0; mt < 4; ++mt)
#pragma unroll
                for (int j = 0; j < 4; ++j) {
                    float bias = cb2[l * 64 + mt * 16 + fq * 4 + j];
#pragma unroll
                    for (int nl = 0; nl < 2; ++nl) {
                        float v = fmaxf(acc[mt][nl][j] + bias, 0.f);
                        oacc[mt][nl][j] = fmaf(m, v, oacc[mt][nl][j]);
                        acc[mt][nl][j] = 0.f;
                    }
                }
        }
        __syncthreads();
    }

    // ---- store partial out1 [blk][64 oc][256 pos] fp32 (two halves per sample) ----
#pragma unroll
    for (int mt = 0; mt < 4; ++mt)
#pragma unroll
        for (int nl = 0; nl < 2; ++nl)
#pragma unroll
            for (int j = 0; j < 4; ++j) {
                int oc = mt * 16 + fq * 4 + j;
                int pos = (wid * 2 + nl) * 16 + fr;
                out1[((size_t)blockIdx.x * 64 + oc) * 256 + pos] = oacc[mt][nl][j];
            }
}

// ---------- fc: sum two leaf-half partials, then [16384] @ [10][16384]^T + b ----------
__global__ __launch_bounds__(256) void k_fc(const float* __restrict__ out1, const float* __restrict__ fcw,
                                            const float* __restrict__ fcb, float* __restrict__ out, int boff) {
    __shared__ float red[4][OUTW_];
    int tid = threadIdx.x;
    int bl = blockIdx.x;
    const float4* f0 = (const float4*)(out1 + (size_t)(bl * 2) * FCIN_);
    const float4* f1 = (const float4*)(out1 + (size_t)(bl * 2 + 1) * FCIN_);
    float pj[OUTW_];
#pragma unroll
    for (int j = 0; j < OUTW_; ++j) pj[j] = 0.f;
    for (int i = tid; i < FCIN_ / 4; i += 256) {
        float4 v0 = f0[i], v1 = f1[i];
        float4 v;
        v.x = v0.x + v1.x; v.y = v0.y + v1.y; v.z = v0.z + v1.z; v.w = v0.w + v1.w;
#pragma unroll
        for (int j = 0; j < OUTW_; ++j) {
            float4 w = ((const float4*)(fcw + (size_t)j * FCIN_))[i];
            pj[j] += v.x * w.x + v.y * w.y + v.z * w.z + v.w * w.w;
        }
    }
#pragma unroll
    for (int j = 0; j < OUTW_; ++j) {
        float v = pj[j];
        for (int off = 32; off > 0; off >>= 1) v += __shfl_xor(v, off);
        if ((tid & 63) == 0) red[tid >> 6][j] = v;
    }
    __syncthreads();
    if (tid < OUTW_) {
        float s = red[0][tid] + red[1][tid] + red[2][tid] + red[3][tid] + fcb[tid];
        out[(size_t)(boff + bl) * OUTW_ + tid] = s;
    }
}

extern "C" void kernel_launch(void* const* d_in, const int* in_sizes, int n_in,
                              void* d_out, int out_size, void* d_ws, size_t ws_size,
                              hipStream_t stream) {
    const float* x   = (const float*)d_in[0];
    const float* nw  = (const float*)d_in[1];
    const float* nb  = (const float*)d_in[2];
    const float* w1  = (const float*)d_in[3];
    const float* cb1 = (const float*)d_in[4];
    const float* w2  = (const float*)d_in[5];
    const float* cb2 = (const float*)d_in[6];
    const float* fcw = (const float*)d_in[7];
    const float* fcb = (const float*)d_in[8];
    float* out = (float*)d_out;

    float*  ws  = (float*)d_ws;
    float*  mix = ws;                       // 2048 f
    float*  w1r = mix + 2048;               // 14336 f
    ushort* w2h = (ushort*)(w1r + 14336);   // 294912 us
    ushort* w2l = w2h + 294912;             // 294912 us
    float*  out1 = (float*)(w2l + 294912);  // Bc * 2 * 16384 f

    // fixed bytes: (2048+14336)*4 + 2*294912*2 = 1245184; out1 per sample = 131072 B
    long avail = (long)ws_size - 1245184L;
    int Bc = (int)(avail / 131072L);
    if (Bc > B_) Bc = B_;
    if (Bc < 1) Bc = 1;

    k_repack_w1<<<(512 * 28 + 255) / 256, 256, 0, stream>>>(w1, w1r);
    k_repack_w2<<<294912 / 256, 256, 0, stream>>>(w2, w2h, w2l);
    k_mixture<<<B_, 256, 0, stream>>>(x, nw, nb, mix);

    for (int boff = 0; boff < B_; boff += Bc) {
        int bc = (B_ - boff < Bc) ? (B_ - boff) : Bc;
        k_fused<<<bc * 2, 512, 0, stream>>>(x, w1r, cb1, w2h, w2l, cb2, mix, out1, boff);
        k_fc<<<bc, 256, 0, stream>>>(out1, fcw, fcb, out, boff);
    }
}

// Round 6
// 177.128 us; speedup vs baseline: 2.3268x; 1.6347x over previous
//
#include <hip/hip_runtime.h>
#include <cstdint>
#include <cstddef>

#define B_ 256
#define IW_ 3072
#define L_ 8
#define NN_ 7
#define FCIN_ 16384
#define OUTW_ 10
#define ICST 40   // ushorts per (row,col) cell: 32 ic + 8 pad

typedef short short8 __attribute__((ext_vector_type(8)));
typedef float f32x4 __attribute__((ext_vector_type(4)));

__device__ __forceinline__ ushort f2bf(float x) {
    uint u = __float_as_uint(x);
    return (ushort)((u + 0x7fffu + ((u >> 16) & 1u)) >> 16);
}
__device__ __forceinline__ float bf2f(ushort b) { return __uint_as_float(((uint)b) << 16); }

// ---------- repack conv1 weights into MFMA frag-linear hi/lo bf16 ----------
// layout: [l8][mt4][lane64][j8] (ushort); oc = mt*16 + (lane&15); k = (lane>>4)*8 + j, k = ic*9+tap, pad 27..31 -> 0
__global__ void k_repack_w1f(const float* __restrict__ w1, ushort* __restrict__ w1fh,
                             ushort* __restrict__ w1fl) {
    int i = blockIdx.x * 256 + threadIdx.x;
    if (i >= 16384) return;
    int j    = i & 7;
    int lane = (i >> 3) & 63;
    int mt   = (i >> 9) & 3;
    int l    = i >> 11;
    int fr = lane & 15, fq = lane >> 4;
    int oc = mt * 16 + fr;
    int k = fq * 8 + j;
    float w = (k < 27) ? w1[(size_t)(l * 64 + oc) * 27 + k] : 0.f;
    ushort hb = f2bf(w);
    w1fh[i] = hb;
    w1fl[i] = f2bf(w - bf2f(hb));
}

// ---------- repack conv2 weights into MFMA frag-linear hi/lo bf16 ----------
// layout: [l8][icc2][tap9][mt4][lane64][j8] (ushort);  oc = mt*16 + (lane&15); ic = icc*32 + (lane>>4)*8 + j
__global__ void k_repack_w2(const float* __restrict__ w2, ushort* __restrict__ w2h,
                            ushort* __restrict__ w2l) {
    int i = blockIdx.x * 256 + threadIdx.x;
    if (i >= 294912) return;
    int j    = i & 7;
    int lane = (i >> 3) & 63;
    int mt   = (i >> 9) & 3;
    int tap  = (i >> 11) % 9;
    int icc  = (i / 18432) & 1;
    int l    = i / 36864;
    int fr = lane & 15, fq = lane >> 4;
    int oc = mt * 16 + fr;
    int ic = icc * 32 + fq * 8 + j;
    float w = w2[(((size_t)l * 64 + oc) * 64 + ic) * 9 + tap];
    ushort hb = f2bf(w);
    w2h[i] = hb;
    w2l[i] = f2bf(w - bf2f(hb));
}

// ---------- mixture: per-sample soft tree weights [B][8] ----------
__global__ __launch_bounds__(256) void k_mixture(const float* __restrict__ x, const float* __restrict__ nw,
                                                 const float* __restrict__ nb, float* __restrict__ mix) {
    __shared__ float red[4 * NN_];
    __shared__ float bes[NN_];
    int b = blockIdx.x, tid = threadIdx.x;
    const float* xb = x + (size_t)b * IW_;
    float p[NN_];
#pragma unroll
    for (int n = 0; n < NN_; ++n) p[n] = 0.f;
    for (int i = tid; i < IW_; i += 256) {
        float xv = xb[i];
#pragma unroll
        for (int n = 0; n < NN_; ++n) p[n] = fmaf(xv, nw[n * IW_ + i], p[n]);
    }
#pragma unroll
    for (int n = 0; n < NN_; ++n) {
        float v = p[n];
        for (int off = 32; off > 0; off >>= 1) v += __shfl_xor(v, off);
        if ((tid & 63) == 0) red[(tid >> 6) * NN_ + n] = v;
    }
    __syncthreads();
    if (tid < NN_) {
        float s = red[tid] + red[NN_ + tid] + red[2 * NN_ + tid] + red[3 * NN_ + tid] + nb[tid];
        bes[tid] = 1.f / (1.f + expf(-s));
    }
    __syncthreads();
    if (tid < L_) {
        int leaf = tid;
        float b0 = bes[0];
        float t0 = ((leaf >> 2) & 1) ? b0 : 1.f - b0;
        float b1v = bes[1 + ((leaf >> 2) & 1)];
        float t1 = ((leaf >> 1) & 1) ? b1v : 1.f - b1v;
        float b2v = bes[3 + ((leaf >> 1) & 3)];
        float t2 = (leaf & 1) ? b2v : 1.f - b2v;
        mix[b * L_ + leaf] = t0 * t1 * t2;
    }
}

// ---------- fully-MFMA fused kernel ----------
// grid = bc*2: block = (sample, leaf-half), 4 leaves x 2 icc = 8 steps.
// conv1 as implicit GEMM: per leaf Y[64oc][1024pos] = W1[64][27pad32] @ im2col(x)[32][1024].
// B-frags (im2col) are leaf-invariant: built once from xpad, held in 64 VGPRs (wave owns 8 ntiles = rows 4w..4w+3).
// Pool 2x2 = max(acc[i],acc[i+2]) + shfl_xor(.,1); pack hi/lo into y tile; conv2 MFMA phase unchanged.
__global__ __launch_bounds__(512, 2) void k_fused(const float* __restrict__ x,
                                                  const ushort* __restrict__ w1fh, const ushort* __restrict__ w1fl,
                                                  const float* __restrict__ cb1,
                                                  const ushort* __restrict__ w2h, const ushort* __restrict__ w2l,
                                                  const float* __restrict__ cb2, const float* __restrict__ mixw,
                                                  float* __restrict__ out1, int boff) {
    __shared__ __align__(16) ushort smem[2 * 324 * ICST];   // 51.84 KB: yh | yl (xpad aliases front)
    ushort* yh = smem;
    ushort* yl = smem + 324 * ICST;
    float* xpad = (float*)smem;                              // 3*34*34 floats = 13.9 KB < yh plane

    int tid = threadIdx.x;
    int bl = blockIdx.x >> 1, half = blockIdx.x & 1;
    int b = boff + bl;
    int lane = tid & 63, wid = tid >> 6;
    int fr = lane & 15, fq = lane >> 4;

    // ---- prologue: xpad zero + fill ----
    for (int i = tid; i < 3 * 34 * 34; i += 512) xpad[i] = 0.f;
    __syncthreads();
    for (int i = tid; i < 3072; i += 512) {
        int ch = i >> 10, rr = (i >> 5) & 31, cc = i & 31;
        xpad[(ch * 34 + rr + 1) * 34 + cc + 1] = x[(size_t)b * IW_ + i];
    }
    __syncthreads();

    // ---- build leaf-invariant conv1 B-frags (im2col) in registers ----
    short8 Bh[8], Bl[8];
#pragma unroll
    for (int i = 0; i < 8; ++i) {
        int nt = wid * 8 + i;
        int pos = nt * 16 + fr;          // pre-pool position, row-major 32x32
        int r = pos >> 5, c = pos & 31;
#pragma unroll
        for (int j = 0; j < 8; ++j) {
            int k = fq * 8 + j;          // k = ic*9 + tap
            float xv = 0.f;
            if (k < 27) {
                int ic = k / 9;
                int tap = k - ic * 9;
                int dr = tap / 3, dc = tap - dr * 3;
                xv = xpad[(ic * 34 + r + dr) * 34 + (c + dc)];
            }
            ushort hb = f2bf(xv);
            Bh[i][j] = (short)hb;
            Bl[i][j] = (short)f2bf(xv - bf2f(hb));
        }
    }
    __syncthreads();
    {   // zero y planes (borders stay zero forever)
        uint4 z; z.x = z.y = z.z = z.w = 0u;
        for (int i = tid; i < (2 * 324 * ICST) / 8; i += 512) ((uint4*)smem)[i] = z;
    }
    __syncthreads();

    f32x4 acc[4][2], oacc[4][2];
#pragma unroll
    for (int mt = 0; mt < 4; ++mt)
#pragma unroll
        for (int nl = 0; nl < 2; ++nl) { acc[mt][nl] = (f32x4)0.f; oacc[mt][nl] = (f32x4)0.f; }

    for (int s = 0; s < 8; ++s) {
        int l = half * 4 + (s >> 1), icc = s & 1;

        // ---- conv1 MFMA phase: produce 32 chans (2 mtiles) of this icc chunk ----
#pragma unroll
        for (int mt2 = 0; mt2 < 2; ++mt2) {
            int mtg = icc * 2 + mt2;
            short8 ah = *(const short8*)(w1fh + ((size_t)(l * 4 + mtg) * 64 + lane) * 8);
            short8 al = *(const short8*)(w1fl + ((size_t)(l * 4 + mtg) * 64 + lane) * 8);
            f32x4 a1[8];
#pragma unroll
            for (int i = 0; i < 8; ++i) {
                f32x4 t = (f32x4)0.f;
                t = __builtin_amdgcn_mfma_f32_16x16x32_bf16(ah, Bh[i], t, 0, 0, 0);
                t = __builtin_amdgcn_mfma_f32_16x16x32_bf16(ah, Bl[i], t, 0, 0, 0);
                t = __builtin_amdgcn_mfma_f32_16x16x32_bf16(al, Bh[i], t, 0, 0, 0);
                a1[i] = t;
            }
            float4 bias4 = *(const float4*)(cb1 + l * 64 + mtg * 16 + fq * 4);
            float bb[4] = {bias4.x, bias4.y, bias4.z, bias4.w};
#pragma unroll
            for (int g = 0; g < 4; ++g) {
                int i = (g & 1) + (g >> 1) * 4;   // {0,1,4,5}; pool partner i+2
                ushort hb[4], lb[4];
#pragma unroll
                for (int j2 = 0; j2 < 4; ++j2) {
                    float m0 = fmaxf(a1[i][j2], a1[i + 2][j2]);
                    float m1 = fmaxf(m0, __shfl_xor(m0, 1));
                    float v = fmaxf(m1 + bb[j2], 0.f);
                    ushort h = f2bf(v);
                    hb[j2] = h;
                    lb[j2] = f2bf(v - bf2f(h));
                }
                if ((fr & 1) == 0) {
                    int pr = 2 * wid + (i >> 2);
                    int pc = ((i & 1) * 16 + fr) >> 1;
                    int off = ((pr + 1) * 18 + (pc + 1)) * ICST + mt2 * 16 + fq * 4;
                    uint2 H, Lw;
                    H.x = (uint)hb[0] | ((uint)hb[1] << 16); H.y = (uint)hb[2] | ((uint)hb[3] << 16);
                    Lw.x = (uint)lb[0] | ((uint)lb[1] << 16); Lw.y = (uint)lb[2] | ((uint)lb[3] << 16);
                    *(uint2*)&yh[off] = H;
                    *(uint2*)&yl[off] = Lw;
                }
            }
        }
        __syncthreads();

        // ---- conv2 MFMA phase: 9 taps, wave tile (4mt x 2nl) ----
        const ushort* wa_h = w2h + (size_t)((l * 2 + icc) * 9) * 4 * 512;
        const ushort* wa_l = w2l + (size_t)((l * 2 + icc) * 9) * 4 * 512;
#pragma unroll
        for (int kh = 0; kh < 3; ++kh)
#pragma unroll
            for (int kw = 0; kw < 3; ++kw) {
                int tap = kh * 3 + kw;
                short8 ah[4], al[4];
#pragma unroll
                for (int mt = 0; mt < 4; ++mt) {
                    ah[mt] = *(const short8*)(wa_h + ((size_t)(tap * 4 + mt) * 64 + lane) * 8);
                    al[mt] = *(const short8*)(wa_l + ((size_t)(tap * 4 + mt) * 64 + lane) * 8);
                }
#pragma unroll
                for (int nl = 0; nl < 2; ++nl) {
                    int off = (((wid * 2 + nl) + kh) * 18 + (fr + kw)) * ICST + fq * 8;
                    short8 bh = *(const short8*)(yh + off);
                    short8 bv = *(const short8*)(yl + off);
#pragma unroll
                    for (int mt = 0; mt < 4; ++mt) {
                        acc[mt][nl] = __builtin_amdgcn_mfma_f32_16x16x32_bf16(ah[mt], bh, acc[mt][nl], 0, 0, 0);
                        acc[mt][nl] = __builtin_amdgcn_mfma_f32_16x16x32_bf16(ah[mt], bv, acc[mt][nl], 0, 0, 0);
                        acc[mt][nl] = __builtin_amdgcn_mfma_f32_16x16x32_bf16(al[mt], bh, acc[mt][nl], 0, 0, 0);
                    }
                }
            }
        if (icc) {  // leaf epilogue: bias + relu + mixture accumulate
            float m = mixw[(size_t)b * 8 + l];
#pragma unroll
            for (int mt = 0; mt < 4; ++mt)
#pragma unroll
                for (int j = 0; j < 4; ++j) {
                    float bias = cb2[l * 64 + mt * 16 + fq * 4 + j];
#pragma unroll
                    for (int nl = 0; nl < 2; ++nl) {
                        float v = fmaxf(acc[mt][nl][j] + bias, 0.f);
                        oacc[mt][nl][j] = fmaf(m, v, oacc[mt][nl][j]);
                        acc[mt][nl][j] = 0.f;
                    }
                }
        }
        __syncthreads();
    }

    // ---- store partial out1 [blk][64 oc][256 pos] fp32 (two halves per sample) ----
#pragma unroll
    for (int mt = 0; mt < 4; ++mt)
#pragma unroll
        for (int nl = 0; nl < 2; ++nl)
#pragma unroll
            for (int j = 0; j < 4; ++j) {
                int oc = mt * 16 + fq * 4 + j;
                int pos = (wid * 2 + nl) * 16 + fr;
                out1[((size_t)blockIdx.x * 64 + oc) * 256 + pos] = oacc[mt][nl][j];
            }
}

// ---------- fc: sum two leaf-half partials, then [16384] @ [10][16384]^T + b ----------
__global__ __launch_bounds__(256) void k_fc(const float* __restrict__ out1, const float* __restrict__ fcw,
                                            const float* __restrict__ fcb, float* __restrict__ out, int boff) {
    __shared__ float red[4][OUTW_];
    int tid = threadIdx.x;
    int bl = blockIdx.x;
    const float4* f0 = (const float4*)(out1 + (size_t)(bl * 2) * FCIN_);
    const float4* f1 = (const float4*)(out1 + (size_t)(bl * 2 + 1) * FCIN_);
    float pj[OUTW_];
#pragma unroll
    for (int j = 0; j < OUTW_; ++j) pj[j] = 0.f;
    for (int i = tid; i < FCIN_ / 4; i += 256) {
        float4 v0 = f0[i], v1 = f1[i];
        float4 v;
        v.x = v0.x + v1.x; v.y = v0.y + v1.y; v.z = v0.z + v1.z; v.w = v0.w + v1.w;
#pragma unroll
        for (int j = 0; j < OUTW_; ++j) {
            float4 w = ((const float4*)(fcw + (size_t)j * FCIN_))[i];
            pj[j] += v.x * w.x + v.y * w.y + v.z * w.z + v.w * w.w;
        }
    }
#pragma unroll
    for (int j = 0; j < OUTW_; ++j) {
        float v = pj[j];
        for (int off = 32; off > 0; off >>= 1) v += __shfl_xor(v, off);
        if ((tid & 63) == 0) red[tid >> 6][j] = v;
    }
    __syncthreads();
    if (tid < OUTW_) {
        float s = red[0][tid] + red[1][tid] + red[2][tid] + red[3][tid] + fcb[tid];
        out[(size_t)(boff + bl) * OUTW_ + tid] = s;
    }
}

extern "C" void kernel_launch(void* const* d_in, const int* in_sizes, int n_in,
                              void* d_out, int out_size, void* d_ws, size_t ws_size,
                              hipStream_t stream) {
    const float* x   = (const float*)d_in[0];
    const float* nw  = (const float*)d_in[1];
    const float* nb  = (const float*)d_in[2];
    const float* w1  = (const float*)d_in[3];
    const float* cb1 = (const float*)d_in[4];
    const float* w2  = (const float*)d_in[5];
    const float* cb2 = (const float*)d_in[6];
    const float* fcw = (const float*)d_in[7];
    const float* fcb = (const float*)d_in[8];
    float* out = (float*)d_out;

    float*  ws   = (float*)d_ws;
    float*  mix  = ws;                        // 2048 f
    ushort* w1fh = (ushort*)(mix + 2048);     // 16384 us
    ushort* w1fl = w1fh + 16384;              // 16384 us
    ushort* w2h  = w1fl + 16384;              // 294912 us
    ushort* w2l  = w2h + 294912;              // 294912 us
    float*  out1 = (float*)(w2l + 294912);    // Bc * 2 * 16384 f

    // fixed bytes: 2048*4 + 2*16384*2 + 2*294912*2 = 1253376; out1 per sample = 131072 B
    long avail = (long)ws_size - 1253376L;
    int Bc = (int)(avail / 131072L);
    if (Bc > B_) Bc = B_;
    if (Bc < 1) Bc = 1;

    k_repack_w1f<<<16384 / 256, 256, 0, stream>>>(w1, w1fh, w1fl);
    k_repack_w2<<<294912 / 256, 256, 0, stream>>>(w2, w2h, w2l);
    k_mixture<<<B_, 256, 0, stream>>>(x, nw, nb, mix);

    for (int boff = 0; boff < B_; boff += Bc) {
        int bc = (B_ - boff < Bc) ? (B_ - boff) : Bc;
        k_fused<<<bc * 2, 512, 0, stream>>>(x, w1fh, w1fl, cb1, w2h, w2l, cb2, mix, out1, boff);
        k_fc<<<bc, 256, 0, stream>>>(out1, fcw, fcb, out, boff);
    }
}